// Round 7
// baseline (141.442 us; speedup 1.0000x reference)
//
#include <hip/hip_runtime.h>

typedef float floatx4 __attribute__((ext_vector_type(4)));
typedef int intx4 __attribute__((ext_vector_type(4)));

#define GN 4096
#define GK 1024
#define BM 256          // block rows (A panel)
#define BN 128          // block cols (B panel)
#define BK 64           // K-bytes per LDS step -> 16 iters, TRIPLE-buffered
#define INVT (1.0f/0.03f)
#define QS 24.0f        // int8 quant scale; dots <= 1024*127^2 < 2^24 (fp32-exact)
#define NCROSS 512      // 16 x 32 cross tiles
#define NINTRA 272      // per modality: 32 diag-band + 240 strict-upper (J>=2I+2)
#define NWG (NCROSS + 2 * NINTRA)   // 1056

static __device__ __forceinline__ int q8(float x) {
    int v = __float2int_rn(x * QS);
    return v < -127 ? -127 : (v > 127 ? 127 : v);
}

// ONE WAVE PER ROW: no LDS, no __syncthreads, 4 coalesced float4 passes.
// (R6: neutral vs per-block version -> prep is not the bottleneck; kept for
// fewer blocks.) All reduced values are exact small ints in fp32.
__global__ __launch_bounds__(256)
void prep_all(const float* __restrict__ brand, const float* __restrict__ post,
              unsigned char* __restrict__ brandq, unsigned char* __restrict__ postq,
              float* __restrict__ inv_brand, float* __restrict__ inv_post,
              float* __restrict__ dvec, float* __restrict__ accs,
              float* __restrict__ out) {
    const int i = (blockIdx.x << 2) + (threadIdx.x >> 6);   // row 0..4095
    const int lane = threadIdx.x & 63;

    const float4* pRow = (const float4*)(post  + (size_t)i * GK);
    const float4* bRow = (const float4*)(brand + (size_t)i * GK);
    int* pOut = (int*)(postq  + (size_t)i * GK);
    int* bOut = (int*)(brandq + (size_t)i * GK);

    float ssp = 0.f, ssb = 0.f, ssd = 0.f;
    #pragma unroll
    for (int j = 0; j < 4; ++j) {
        const int idx = j * 64 + lane;
        float4 pv = pRow[idx];
        float4 bv = bRow[idx];
        int p0 = q8(pv.x), p1 = q8(pv.y), p2 = q8(pv.z), p3 = q8(pv.w);
        int b0 = q8(bv.x), b1 = q8(bv.y), b2 = q8(bv.z), b3 = q8(bv.w);
        pOut[idx] = (p0 & 255) | ((p1 & 255) << 8) | ((p2 & 255) << 16) | ((p3 & 255) << 24);
        bOut[idx] = (b0 & 255) | ((b1 & 255) << 8) | ((b2 & 255) << 16) | ((b3 & 255) << 24);
        ssp += (float)(p0 * p0 + p1 * p1 + p2 * p2 + p3 * p3);
        ssb += (float)(b0 * b0 + b1 * b1 + b2 * b2 + b3 * b3);
        ssd += (float)(p0 * b0 + p1 * b1 + p2 * b2 + p3 * b3);
    }
    #pragma unroll
    for (int off = 32; off > 0; off >>= 1) {
        ssp += __shfl_down(ssp, off);
        ssb += __shfl_down(ssb, off);
        ssd += __shfl_down(ssd, off);
    }
    if (lane == 0) {
        inv_post[i]  = 1.0f / sqrtf(ssp);
        inv_brand[i] = 1.0f / sqrtf(ssb);
        dvec[i]      = ssd;
    } else if (lane == 1) accs[i] = 0.f;
    else if (lane == 2) accs[GN + i] = 0.f;
    else if (lane == 3) accs[2 * GN + i] = 0.f;
    else if (lane == 4) accs[3 * GN + i] = 0.f;
    else if (lane == 5 && i == 0) out[0] = 0.f;
}

// Unified GEMM, int8 16x16x64 MFMA. R4 schedule (triple-buffer, counted
// vmcnt, depth-2 DMA prefetch) kept verbatim; blocking enlarged to cut the
// LDS-port wall R4's counters exposed (LDS 1.57x the MFMA wall at 64x64/wave;
// reads/FLOP is invariant to block size at fixed wave-tile -> must grow the
// per-wave tile): block 256x128, 4 waves in 2x2, per-wave 128x64 (acc 8x4).
// Reads/FLOP 1/64 -> 1/85; MFMA:ds_read 1.33 -> 2.67.
// LDS = 3 x (256+128) x 64 = 72 KB -> 2 blocks/CU (8 waves/CU, as measured).
// Per iter per wave: STAGE = 6 global_load_lds (4 A + 2 B), so steady-state
// wait is vmcnt(6) (the STAGE just issued stays in flight). Swizzle as R4:
// global chunk g of row r at LDS slot g^((r>>2)&3); DMA dest linear, inverse
// XOR pre-applied to the per-lane GLOBAL source (both-sides-or-neither).
#define AS1C (const __attribute__((address_space(1))) void*)
#define AS3C (__attribute__((address_space(3))) void*)

// stage 64-B K-slice k0 of both panels into buffer b (6 instr/wave, 1 KB each)
// wave stages A rows [wave*64, wave*64+64) and B rows [wave*32, wave*32+32)
#define STAGE(b, k0) do { \
    unsigned char* _a = smem + (b) * 24576 + wave * 4096; \
    unsigned char* _bd = smem + (b) * 24576 + 16384 + wave * 2048; \
    _Pragma("unroll") \
    for (int _s = 0; _s < 4; ++_s) \
        __builtin_amdgcn_global_load_lds(AS1C(aSrc + (size_t)_s * 16 * GK + (k0)), \
                                         AS3C(_a + _s * 1024), 16, 0, 0); \
    _Pragma("unroll") \
    for (int _s = 0; _s < 2; ++_s) \
        __builtin_amdgcn_global_load_lds(AS1C(bSrc + (size_t)_s * 16 * GK + (k0)), \
                                         AS3C(_bd + _s * 1024), 16, 0, 0); \
} while (0)

#define KITER(b) do { \
    const unsigned char* As_ = smem + (b) * 24576; \
    const unsigned char* Bs_ = As_ + 16384; \
    intx4 af[8], bfr[4]; \
    _Pragma("unroll") \
    for (int _u = 0; _u < 4; ++_u) \
        bfr[_u] = *(const intx4*)(Bs_ + bOff + _u * 1024); \
    _Pragma("unroll") \
    for (int _m = 0; _m < 8; ++_m) \
        af[_m] = *(const intx4*)(As_ + aOff + _m * 1024); \
    _Pragma("unroll") \
    for (int _t = 0; _t < 8; ++_t) \
        _Pragma("unroll") \
        for (int _u = 0; _u < 4; ++_u) \
            acc[_t][_u] = __builtin_amdgcn_mfma_i32_16x16x64_i8( \
                af[_t], bfr[_u], acc[_t][_u], 0, 0, 0); \
} while (0)

#define WAITBAR6() asm volatile("s_waitcnt vmcnt(6)\n\ts_barrier" ::: "memory")
#define WAITBAR0() asm volatile("s_waitcnt vmcnt(0)\n\ts_barrier" ::: "memory")

__global__ __launch_bounds__(256, 2)
void gemm_all(const unsigned char* __restrict__ postq, const unsigned char* __restrict__ brandq,
              const float* __restrict__ dvec,
              const float* __restrict__ inv_post, const float* __restrict__ inv_brand,
              float* __restrict__ sum_post, float* __restrict__ cnt_post,
              float* __restrict__ sum_brand, float* __restrict__ cnt_brand) {
    __shared__ __align__(16) unsigned char smem[3 * (BM + BN) * BK];   // 72 KB; epilogue alias

    const int tid = threadIdx.x;
    const int wave = tid >> 6, lane = tid & 63;
    const int wm = (wave >> 1) * 128;      // 2 row-halves of 128
    const int wn = (wave & 1) * 64;        // 2 col-halves of 64

    int idx = blockIdx.x;

    const unsigned char *A, *B;
    const float *invA, *invB;
    float *srow, *scol, *crow, *ccol;
    int bm, bn;
    float iaScale;
    bool is_cross, do_cols;

    if (idx < NCROSS) {
        is_cross = true; do_cols = true;
        bm = (idx >> 5) * BM; bn = (idx & 31) * BN;    // 16 x 32
        A = postq; B = brandq;
        invA = inv_post; invB = inv_brand; iaScale = INVT;
        srow = sum_post; crow = cnt_post; scol = sum_brand; ccol = cnt_brand;
    } else {
        is_cross = false;
        idx -= NCROSS;
        const unsigned char* X; const float* invx; float* sacc;
        if (idx >= NINTRA) { idx -= NINTRA; X = brandq; invx = inv_brand; sacc = sum_brand; }
        else               {                X = postq;  invx = inv_post;  sacc = sum_post;  }
        int I, J;
        if (idx < 32) {                     // diagonal band: J in {2I, 2I+1}
            I = idx >> 1; J = 2 * I + (idx & 1);
            do_cols = false;
        } else {                            // strict upper: J >= 2I+2
            const int e = idx - 32;         // 0..239, cum(I) = I*(31-I)
            I = (int)((31.f - sqrtf(961.f - 4.f * e)) * 0.5f);
            while ((I + 1) * (30 - I) <= e) ++I;
            while (I * (31 - I) > e) --I;
            J = 2 * I + 2 + (e - I * (31 - I));
            do_cols = true;
        }
        bm = I * BM; bn = J * BN;
        A = X; B = X;
        invA = invx; invB = invx; iaScale = 0.8f * INVT;
        srow = sacc; scol = sacc; crow = nullptr; ccol = nullptr;
    }

    const int lrow = lane & 15;
    const int kq = lane >> 4;                 // 0..3

    // DMA: lane l -> row l>>2 (16 rows/instr), LDS slot l&3 (linear dest),
    // global chunk (l&3)^((l>>4)&3) = slot ^ ((row>>2)&3), row = base16 + (l>>2).
    const size_t dma_off = (size_t)(lane >> 2) * GK
                         + ((((lane & 3) ^ ((lane >> 4) & 3))) * 16);
    const unsigned char* aSrc = A + (size_t)(bm + wave * 64) * GK + dma_off;
    const unsigned char* bSrc = B + (size_t)(bn + wave * 32) * GK + dma_off;

    // fragment read: row = (wm|wn) + m*16 + lrow -> (row>>2)&3 = (lrow>>2)&3
    const int cx = ((kq ^ ((lrow >> 2) & 3)) * 16);
    const int aOff = (wm + lrow) * BK + cx;
    const int bOff = (wn + lrow) * BK + cx;

    intx4 acc[8][4] = {};

    // prologue: stage tiles 0,1; wait tile 0 only (tile 1's 6 stay in flight)
    STAGE(0, 0); STAGE(1, 64);
    WAITBAR6();

    // steady state: t = 0..11 (stage tiles 2..13), buffers rotate 0,1,2
    #pragma unroll 1
    for (int k = 0; k < 768; k += 192) {
        STAGE(2, k + 128); KITER(0); WAITBAR6();
        STAGE(0, k + 192); KITER(1); WAITBAR6();
        STAGE(1, k + 256); KITER(2); WAITBAR6();
    }
    // tail: t = 12..15
    STAGE(2, 896); KITER(0); WAITBAR6();   // t=12, stage tile 14
    STAGE(0, 960); KITER(1); WAITBAR6();   // t=13, stage tile 15
    KITER(2); WAITBAR0();                  // t=14, drain tile 15
    KITER(0);                              // t=15
    __syncthreads();                       // separates tile reads from epilogue alias

    // ---- epilogue (C/D: col=lane&15, row=(lane>>4)*4+reg; shape-determined) ----
    const int cn = lane & 15, rq = lane >> 4;
    float ib_c[4], db_c[4];
    #pragma unroll
    for (int u = 0; u < 4; ++u) {
        const int gc = bn + wn + u * 16 + cn;
        ib_c[u] = invB[gc];
        db_c[u] = is_cross ? dvec[gc] : 0.f;
    }

    float csum[4] = {}, ccnt[4] = {};
    float my_rs[2] = {}, my_rc[2] = {};
    #pragma unroll
    for (int t8 = 0; t8 < 8; ++t8) {
        #pragma unroll
        for (int r = 0; r < 4; ++r) {
            const int rl = wm + t8 * 16 + rq * 4 + r;
            const int grow = bm + rl;
            const float ia = invA[grow] * iaScale;
            float v = 0.f, w = 0.f;
            if (is_cross) {
                const float da = dvec[grow];
                #pragma unroll
                for (int u = 0; u < 4; ++u) {
                    const float s = (float)acc[t8][u][r];   // exact int < 2^24
                    const int gcol = bn + wn + u * 16 + cn;
                    const bool diag = (grow == gcol);
                    float e = __expf(s * ia * ib_c[u]);
                    v += e;
                    csum[u] += e;
                    w += (!diag && s > da) ? 1.f : 0.f;
                    ccnt[u] += (!diag && s > db_c[u]) ? 1.f : 0.f;
                }
                w += __shfl_xor(w, 1); w += __shfl_xor(w, 2);
                w += __shfl_xor(w, 4); w += __shfl_xor(w, 8);
            } else {
                #pragma unroll
                for (int u = 0; u < 4; ++u) {
                    const float s = (float)acc[t8][u][r];
                    const int gcol = bn + wn + u * 16 + cn;
                    float e = (grow == gcol) ? 1.0f : __expf(s * ia * ib_c[u]);
                    v += e;
                    csum[u] += e;
                }
            }
            v += __shfl_xor(v, 1); v += __shfl_xor(v, 2);
            v += __shfl_xor(v, 4); v += __shfl_xor(v, 8);
            const int p = t8 * 4 + r;                // 0..31 row-slots, 16 cn lanes
            if (cn == (p & 15)) { my_rs[p >> 4] = v; my_rc[p >> 4] = w; }
        }
    }

    // reduction scratch aliases the (dead) tile LDS
    float (*redRS)[2] = (float(*)[2])(smem);             // 256 rows x 2 (wn half)
    float (*redRC)[2] = (float(*)[2])(smem + 2048);
    float (*redCS)[2] = (float(*)[2])(smem + 4096);      // 128 cols x 2 (wm half)
    float (*redCC)[2] = (float(*)[2])(smem + 5120);

    const int rlA = wm + (cn >> 2) * 16 + rq * 4 + (cn & 3);
    redRS[rlA][wave & 1]      = my_rs[0];
    redRS[rlA + 64][wave & 1] = my_rs[1];
    redRC[rlA][wave & 1]      = my_rc[0];
    redRC[rlA + 64][wave & 1] = my_rc[1];

    float my_cs = 0.f, my_cc = 0.f;
    #pragma unroll
    for (int u = 0; u < 4; ++u) {
        float v = csum[u];
        v += __shfl_xor(v, 16); v += __shfl_xor(v, 32);
        if (rq == u) my_cs = v;
        if (is_cross) {
            float w = ccnt[u];
            w += __shfl_xor(w, 16); w += __shfl_xor(w, 32);
            if (rq == u) my_cc = w;
        }
    }
    const int clA = wn + rq * 16 + cn;
    redCS[clA][wave >> 1] = my_cs;
    redCC[clA][wave >> 1] = my_cc;
    __syncthreads();

    atomicAdd(&srow[bm + tid], redRS[tid][0] + redRS[tid][1]);
    if (is_cross) atomicAdd(&crow[bm + tid], redRC[tid][0] + redRC[tid][1]);
    if (do_cols && tid < 128) {
        atomicAdd(&scol[bn + tid], redCS[tid][0] + redCS[tid][1]);
        if (is_cross) atomicAdd(&ccol[bn + tid], redCC[tid][0] + redCC[tid][1]);
    }
}

// Final per-row loss assembly + global sum
__global__ __launch_bounds__(256)
void final_loss(const float* __restrict__ sum_post, const float* __restrict__ cnt_post,
                const float* __restrict__ sum_brand, const float* __restrict__ cnt_brand,
                const float* __restrict__ dvec,
                const float* __restrict__ inv_post, const float* __restrict__ inv_brand,
                float* __restrict__ out) {
    const int i = blockIdx.x * 256 + threadIdx.x;
    float dl = dvec[i] * inv_post[i] * inv_brand[i] * INVT;
    float lp = logf(sum_post[i]);
    float lb = logf(sum_brand[i]);
    float rp = 1.0f / (4096.0f - cnt_post[i]) + 1.0f;
    float rb = 1.0f / (4096.0f - cnt_brand[i]) + 1.0f;
    float loss = 0.5f * (rb * (lb - dl) + rp * (lp - dl));
    #pragma unroll
    for (int off = 32; off > 0; off >>= 1) loss += __shfl_down(loss, off);
    __shared__ float sw[4];
    int wave = threadIdx.x >> 6, lane = threadIdx.x & 63;
    if (lane == 0) sw[wave] = loss;
    __syncthreads();
    if (threadIdx.x == 0) atomicAdd(out, sw[0] + sw[1] + sw[2] + sw[3]);
}

extern "C" void kernel_launch(void* const* d_in, const int* in_sizes, int n_in,
                              void* d_out, int out_size, void* d_ws, size_t ws_size,
                              hipStream_t stream) {
    const float* brand = (const float*)d_in[0];
    const float* post  = (const float*)d_in[1];
    float* out = (float*)d_out;

    char* ws = (char*)d_ws;
    unsigned char* postq  = (unsigned char*)ws;                          // 4 MB
    unsigned char* brandq = postq + (size_t)GN * GK;                     // 4 MB
    float* inv_post  = (float*)(brandq + (size_t)GN * GK);
    float* inv_brand = inv_post + GN;
    float* dvec      = inv_brand + GN;
    float* accs      = dvec + GN;        // [sum_post, sum_brand, cnt_post, cnt_brand]
    float* sum_post  = accs;
    float* sum_brand = accs + GN;
    float* cnt_post  = accs + 2 * GN;
    float* cnt_brand = accs + 3 * GN;

    prep_all<<<GN / 4, 256, 0, stream>>>(brand, post, brandq, postq,
                                         inv_brand, inv_post, dvec, accs, out);
    gemm_all<<<NWG, 256, 0, stream>>>(postq, brandq, dvec,
                                      inv_post, inv_brand,
                                      sum_post, cnt_post,
                                      sum_brand, cnt_brand);
    final_loss<<<GN / 256, 256, 0, stream>>>(sum_post, cnt_post, sum_brand, cnt_brand,
                                             dvec, inv_post, inv_brand, out);
}

// Round 8
// 130.912 us; speedup vs baseline: 1.0804x; 1.0804x over previous
//
#include <hip/hip_runtime.h>

typedef float floatx4 __attribute__((ext_vector_type(4)));
typedef int intx4 __attribute__((ext_vector_type(4)));

#define GN 4096
#define GK 1024
#define BM 128
#define BN 128
#define BK 64           // K-bytes per LDS step -> 16 iters
#define INVT (1.0f/0.03f)
#define QS 24.0f        // int8 quant scale; dots <= 1024*127^2 < 2^24 (fp32-exact)
#define NTILES 528      // 32*33/2 upper-tri tiles per modality
#define NCROSS 1024     // 32*32 cross tiles
#define NWG (NCROSS + 2 * NTILES)   // 2080

static __device__ __forceinline__ int q8(float x) {
    int v = __float2int_rn(x * QS);
    return v < -127 ? -127 : (v > 127 ? 127 : v);
}

// ONE WAVE PER ROW: no LDS, no __syncthreads, 4 coalesced float4 passes.
__global__ __launch_bounds__(256)
void prep_all(const float* __restrict__ brand, const float* __restrict__ post,
              unsigned char* __restrict__ brandq, unsigned char* __restrict__ postq,
              float* __restrict__ inv_brand, float* __restrict__ inv_post,
              float* __restrict__ dvec, float* __restrict__ accs,
              float* __restrict__ out) {
    const int i = (blockIdx.x << 2) + (threadIdx.x >> 6);   // row 0..4095
    const int lane = threadIdx.x & 63;

    const float4* pRow = (const float4*)(post  + (size_t)i * GK);
    const float4* bRow = (const float4*)(brand + (size_t)i * GK);
    int* pOut = (int*)(postq  + (size_t)i * GK);
    int* bOut = (int*)(brandq + (size_t)i * GK);

    float ssp = 0.f, ssb = 0.f, ssd = 0.f;
    #pragma unroll
    for (int j = 0; j < 4; ++j) {
        const int idx = j * 64 + lane;
        float4 pv = pRow[idx];
        float4 bv = bRow[idx];
        int p0 = q8(pv.x), p1 = q8(pv.y), p2 = q8(pv.z), p3 = q8(pv.w);
        int b0 = q8(bv.x), b1 = q8(bv.y), b2 = q8(bv.z), b3 = q8(bv.w);
        pOut[idx] = (p0 & 255) | ((p1 & 255) << 8) | ((p2 & 255) << 16) | ((p3 & 255) << 24);
        bOut[idx] = (b0 & 255) | ((b1 & 255) << 8) | ((b2 & 255) << 16) | ((b3 & 255) << 24);
        ssp += (float)(p0 * p0 + p1 * p1 + p2 * p2 + p3 * p3);
        ssb += (float)(b0 * b0 + b1 * b1 + b2 * b2 + b3 * b3);
        ssd += (float)(p0 * b0 + p1 * b1 + p2 * b2 + p3 * b3);
    }
    #pragma unroll
    for (int off = 32; off > 0; off >>= 1) {
        ssp += __shfl_down(ssp, off);
        ssb += __shfl_down(ssb, off);
        ssd += __shfl_down(ssd, off);
    }
    if (lane == 0) {
        inv_post[i]  = 1.0f / sqrtf(ssp);
        inv_brand[i] = 1.0f / sqrtf(ssb);
        dvec[i]      = ssd;
    } else if (lane == 1) accs[i] = 0.f;
    else if (lane == 2) accs[GN + i] = 0.f;
    else if (lane == 3) accs[2 * GN + i] = 0.f;
    else if (lane == 4) accs[3 * GN + i] = 0.f;
    else if (lane == 5 && i == 0) out[0] = 0.f;
}

// Unified GEMM, int8 16x16x64 MFMA. R4 pipeline (counted vmcnt, depth-2 A
// prefetch) on the proven 128x128 / 4-wave / 64x64-per-wave geometry, with
// occupancy raised 3 -> 4 blocks/CU (12 -> 16 waves). R7 showed the kernel is
// latency-bound (both pipes ~50% idle at 2 waves/SIMD); both caps moved:
//  - LDS 48 -> 40 KB: A triple-buffered (3x8K, 2-iter prefetch depth kept),
//    B double-buffered (2x8K, covered by one KITER + TLP). 4 x 40KB = 160KB.
//  - regs <= 128 unified via __launch_bounds__(256,4) (live set ~110).
// Per iter: {STAGE_B(t+1)[2 loads] -> STAGE_A(t+2)[2 loads] -> KITER(t) ->
// vmcnt(2); barrier}. In-order retirement: the wait retires A(t+1)+B(t+1),
// leaves A(t+2) in flight (never drains to 0 until the tail).
// Swizzle as R4: global chunk g of row r at LDS slot g^((r>>2)&3); DMA dest
// linear, inverse XOR pre-applied to the per-lane GLOBAL source.
#define AS1C (const __attribute__((address_space(1))) void*)
#define AS3C (__attribute__((address_space(3))) void*)

#define STAGE_A(b, k0) do { \
    unsigned char* _d = smem + (b) * 8192 + wave * 2048; \
    __builtin_amdgcn_global_load_lds(AS1C(aSrc + (k0)),           AS3C(_d),        16, 0, 0); \
    __builtin_amdgcn_global_load_lds(AS1C(aSrc + 16 * GK + (k0)), AS3C(_d + 1024), 16, 0, 0); \
} while (0)
#define STAGE_B(b, k0) do { \
    unsigned char* _d = smem + 24576 + (b) * 8192 + wave * 2048; \
    __builtin_amdgcn_global_load_lds(AS1C(bSrc + (k0)),           AS3C(_d),        16, 0, 0); \
    __builtin_amdgcn_global_load_lds(AS1C(bSrc + 16 * GK + (k0)), AS3C(_d + 1024), 16, 0, 0); \
} while (0)

#define KITER(a, b) do { \
    const unsigned char* As_ = smem + (a) * 8192; \
    const unsigned char* Bs_ = smem + 24576 + (b) * 8192; \
    intx4 af[4], bfr[4]; \
    _Pragma("unroll") \
    for (int _u = 0; _u < 4; ++_u) \
        bfr[_u] = *(const intx4*)(Bs_ + bOff + _u * 1024); \
    _Pragma("unroll") \
    for (int _m = 0; _m < 4; ++_m) \
        af[_m] = *(const intx4*)(As_ + aOff + _m * 1024); \
    _Pragma("unroll") \
    for (int _t = 0; _t < 4; ++_t) \
        _Pragma("unroll") \
        for (int _u = 0; _u < 4; ++_u) \
            acc[_t][_u] = __builtin_amdgcn_mfma_i32_16x16x64_i8( \
                af[_t], bfr[_u], acc[_t][_u], 0, 0, 0); \
} while (0)

#define VM2BAR() asm volatile("s_waitcnt vmcnt(2)\n\ts_barrier" ::: "memory")
#define VM0BAR() asm volatile("s_waitcnt vmcnt(0)\n\ts_barrier" ::: "memory")

__global__ __launch_bounds__(256, 4)
void gemm_all(const unsigned char* __restrict__ postq, const unsigned char* __restrict__ brandq,
              const float* __restrict__ dvec,
              const float* __restrict__ inv_post, const float* __restrict__ inv_brand,
              float* __restrict__ sum_post, float* __restrict__ cnt_post,
              float* __restrict__ sum_brand, float* __restrict__ cnt_brand) {
    __shared__ __align__(16) unsigned char smem[(3 + 2) * BM * BK];   // 40 KB; epilogue alias

    const int tid = threadIdx.x;
    const int wave = tid >> 6, lane = tid & 63;
    const int wm = (wave >> 1) * 64, wn = (wave & 1) * 64;

    int idx = blockIdx.x;

    const unsigned char *A, *B;
    const float *invA, *invB;
    float *srow, *scol, *crow, *ccol;
    int bm, bn;
    float iaScale;
    bool is_cross, do_cols;

    if (idx < NCROSS) {
        is_cross = true; do_cols = true;
        bm = (idx >> 5) * BM; bn = (idx & 31) * BN;
        A = postq; B = brandq;
        invA = inv_post; invB = inv_brand; iaScale = INVT;
        srow = sum_post; crow = cnt_post; scol = sum_brand; ccol = cnt_brand;
    } else {
        is_cross = false;
        idx -= NCROSS;
        const unsigned char* X; const float* invx; float* sacc;
        if (idx >= NTILES) { idx -= NTILES; X = brandq; invx = inv_brand; sacc = sum_brand; }
        else               {               X = postq;  invx = inv_post;  sacc = sum_post;  }
        int J = (int)((sqrtf(8.f * idx + 1.f) - 1.f) * 0.5f);
        while ((J + 1) * (J + 2) / 2 <= idx) ++J;
        while (J * (J + 1) / 2 > idx) --J;
        const int I = idx - J * (J + 1) / 2;
        bm = I * BM; bn = J * BN;
        A = X; B = X;
        invA = invx; invB = invx; iaScale = 0.8f * INVT;
        srow = sacc; scol = sacc; crow = nullptr; ccol = nullptr;
        do_cols = (I != J);
    }

    const int lrow = lane & 15;
    const int kq = lane >> 4;                 // 0..3

    // DMA: lane l -> row l>>2 (16 rows/instr), LDS slot l&3 (linear dest),
    // global chunk (l&3)^((l>>4)&3) = slot ^ ((row>>2)&3), row = base16 + (l>>2).
    const size_t dma_off = (size_t)(lane >> 2) * GK
                         + ((((lane & 3) ^ ((lane >> 4) & 3))) * 16);
    const unsigned char* aSrc = A + (size_t)(bm + wave * 32) * GK + dma_off;
    const unsigned char* bSrc = B + (size_t)(bn + wave * 32) * GK + dma_off;

    // fragment read: row = (wm|wn) + m*16 + lrow -> (row>>2)&3 = (lrow>>2)&3
    const int cx = ((kq ^ ((lrow >> 2) & 3)) * 16);
    const int aOff = (wm + lrow) * BK + cx;
    const int bOff = (wn + lrow) * BK + cx;

    intx4 acc[4][4] = {};

    // prologue: B(0)->b0, A(0)->a0, A(1)->a1; retire B0+A0, leave A1 in flight
    STAGE_B(0, 0); STAGE_A(0, 0); STAGE_A(1, 64);
    VM2BAR();

    // steady state: t = 0..11 (A bufs t%3, B bufs t&1; period lcm = 6)
    #pragma unroll 1
    for (int k = 0; k < 768; k += 384) {
        STAGE_B(1, k +  64); STAGE_A(2, k + 128); KITER(0, 0); VM2BAR();
        STAGE_B(0, k + 128); STAGE_A(0, k + 192); KITER(1, 1); VM2BAR();
        STAGE_B(1, k + 192); STAGE_A(1, k + 256); KITER(2, 0); VM2BAR();
        STAGE_B(0, k + 256); STAGE_A(2, k + 320); KITER(0, 1); VM2BAR();
        STAGE_B(1, k + 320); STAGE_A(0, k + 384); KITER(1, 0); VM2BAR();
        STAGE_B(0, k + 384); STAGE_A(1, k + 448); KITER(2, 1); VM2BAR();
    }
    // tail: t = 12..15
    STAGE_B(1, 832); STAGE_A(2, 896); KITER(0, 0); VM2BAR();   // t=12
    STAGE_B(0, 896); STAGE_A(0, 960); KITER(1, 1); VM2BAR();   // t=13
    STAGE_B(1, 960);                  KITER(2, 0); VM0BAR();   // t=14
                                      KITER(0, 1);             // t=15
    __syncthreads();                  // separates tile reads from epilogue alias

    // ---- epilogue (C/D: col=lane&15, row=(lane>>4)*4+reg; shape-determined) ----
    const int cn = lane & 15, rq = lane >> 4;
    float ib_c[4], db_c[4];
    #pragma unroll
    for (int u = 0; u < 4; ++u) {
        const int gc = bn + wn + u * 16 + cn;
        ib_c[u] = invB[gc];
        db_c[u] = is_cross ? dvec[gc] : 0.f;
    }

    float csum[4] = {}, ccnt[4] = {};
    float my_rs = 0.f, my_rc = 0.f;
    #pragma unroll
    for (int t = 0; t < 4; ++t) {
        #pragma unroll
        for (int r = 0; r < 4; ++r) {
            const int rl = wm + t * 16 + rq * 4 + r;
            const int grow = bm + rl;
            const float ia = invA[grow] * iaScale;
            float v = 0.f, w = 0.f;
            if (is_cross) {
                const float da = dvec[grow];
                #pragma unroll
                for (int u = 0; u < 4; ++u) {
                    const float s = (float)acc[t][u][r];   // exact int < 2^24
                    const int gcol = bn + wn + u * 16 + cn;
                    const bool diag = (grow == gcol);
                    float e = __expf(s * ia * ib_c[u]);
                    v += e;
                    csum[u] += e;
                    w += (!diag && s > da) ? 1.f : 0.f;
                    ccnt[u] += (!diag && s > db_c[u]) ? 1.f : 0.f;
                }
                w += __shfl_xor(w, 1); w += __shfl_xor(w, 2);
                w += __shfl_xor(w, 4); w += __shfl_xor(w, 8);
            } else {
                #pragma unroll
                for (int u = 0; u < 4; ++u) {
                    const float s = (float)acc[t][u][r];
                    const int gcol = bn + wn + u * 16 + cn;
                    float e = (grow == gcol) ? 1.0f : __expf(s * ia * ib_c[u]);
                    v += e;
                    csum[u] += e;
                }
            }
            v += __shfl_xor(v, 1); v += __shfl_xor(v, 2);
            v += __shfl_xor(v, 4); v += __shfl_xor(v, 8);
            if (cn == ((t << 2) | r)) { my_rs = v; my_rc = w; }
        }
    }

    // reduction scratch aliases the (dead) tile LDS
    float (*redRS)[2] = (float(*)[2])(smem);
    float (*redRC)[2] = (float(*)[2])(smem + 1024);
    float (*redCS)[2] = (float(*)[2])(smem + 2048);
    float (*redCC)[2] = (float(*)[2])(smem + 3072);

    const int rl_local = wm + (cn >> 2) * 16 + rq * 4 + (cn & 3);
    redRS[rl_local][wave & 1] = my_rs;
    redRC[rl_local][wave & 1] = my_rc;

    float my_cs = 0.f, my_cc = 0.f;
    #pragma unroll
    for (int u = 0; u < 4; ++u) {
        float v = csum[u];
        v += __shfl_xor(v, 16); v += __shfl_xor(v, 32);
        if (rq == u) my_cs = v;
        if (is_cross) {
            float w = ccnt[u];
            w += __shfl_xor(w, 16); w += __shfl_xor(w, 32);
            if (rq == u) my_cc = w;
        }
    }
    const int cl_local = wn + rq * 16 + cn;
    redCS[cl_local][wave >> 1] = my_cs;
    redCC[cl_local][wave >> 1] = my_cc;
    __syncthreads();

    if (tid < 128) {
        atomicAdd(&srow[bm + tid], redRS[tid][0] + redRS[tid][1]);
        if (is_cross) atomicAdd(&crow[bm + tid], redRC[tid][0] + redRC[tid][1]);
    } else if (do_cols) {
        const int t2 = tid - 128;
        atomicAdd(&scol[bn + t2], redCS[t2][0] + redCS[t2][1]);
        if (is_cross) atomicAdd(&ccol[bn + t2], redCC[t2][0] + redCC[t2][1]);
    }
}

// Final per-row loss assembly + global sum
__global__ __launch_bounds__(256)
void final_loss(const float* __restrict__ sum_post, const float* __restrict__ cnt_post,
                const float* __restrict__ sum_brand, const float* __restrict__ cnt_brand,
                const float* __restrict__ dvec,
                const float* __restrict__ inv_post, const float* __restrict__ inv_brand,
                float* __restrict__ out) {
    const int i = blockIdx.x * 256 + threadIdx.x;
    float dl = dvec[i] * inv_post[i] * inv_brand[i] * INVT;
    float lp = logf(sum_post[i]);
    float lb = logf(sum_brand[i]);
    float rp = 1.0f / (4096.0f - cnt_post[i]) + 1.0f;
    float rb = 1.0f / (4096.0f - cnt_brand[i]) + 1.0f;
    float loss = 0.5f * (rb * (lb - dl) + rp * (lp - dl));
    #pragma unroll
    for (int off = 32; off > 0; off >>= 1) loss += __shfl_down(loss, off);
    __shared__ float sw[4];
    int wave = threadIdx.x >> 6, lane = threadIdx.x & 63;
    if (lane == 0) sw[wave] = loss;
    __syncthreads();
    if (threadIdx.x == 0) atomicAdd(out, sw[0] + sw[1] + sw[2] + sw[3]);
}

extern "C" void kernel_launch(void* const* d_in, const int* in_sizes, int n_in,
                              void* d_out, int out_size, void* d_ws, size_t ws_size,
                              hipStream_t stream) {
    const float* brand = (const float*)d_in[0];
    const float* post  = (const float*)d_in[1];
    float* out = (float*)d_out;

    char* ws = (char*)d_ws;
    unsigned char* postq  = (unsigned char*)ws;                          // 4 MB
    unsigned char* brandq = postq + (size_t)GN * GK;                     // 4 MB
    float* inv_post  = (float*)(brandq + (size_t)GN * GK);
    float* inv_brand = inv_post + GN;
    float* dvec      = inv_brand + GN;
    float* accs      = dvec + GN;        // [sum_post, sum_brand, cnt_post, cnt_brand]
    float* sum_post  = accs;
    float* sum_brand = accs + GN;
    float* cnt_post  = accs + 2 * GN;
    float* cnt_brand = accs + 3 * GN;

    prep_all<<<GN / 4, 256, 0, stream>>>(brand, post, brandq, postq,
                                         inv_brand, inv_post, dvec, accs, out);
    gemm_all<<<NWG, 256, 0, stream>>>(postq, brandq, dvec,
                                      inv_post, inv_brand,
                                      sum_post, cnt_post,
                                      sum_brand, cnt_brand);
    final_loss<<<GN / 256, 256, 0, stream>>>(sum_post, cnt_post, sum_brand, cnt_brand,
                                             dvec, inv_post, inv_brand, out);
}